// Round 2
// baseline (70075.342 us; speedup 1.0000x reference)
//
#include <hip/hip_runtime.h>

#define NN 5000
#define EE 80000
#define BB 16
#define TT 64
// HG=64, HT=128

constexpr int NPB  = 64;    // nodes per conv2 block
constexpr int ECAP = 1280;  // LDS edge-stage capacity (mean 1024, +8 sigma)

// ---------------- CSR build ----------------
__global__ void k_deg(const int* __restrict__ dst, int* __restrict__ deg) {
  int e = blockIdx.x * 256 + threadIdx.x;
  if (e < EE) atomicAdd(&deg[dst[e]], 1);
}

__global__ __launch_bounds__(1024) void k_scan(const int* __restrict__ deg,
                                               int* __restrict__ rowptr,
                                               float* __restrict__ invdeg) {
  __shared__ int part[1024];
  int t = threadIdx.x;
  const int CH = 5;                      // 1024*5 >= 5000
  int base = t * CH;
  int cnt[CH];
  int s = 0;
  for (int i = 0; i < CH; ++i) { int idx = base + i; int d = (idx < NN) ? deg[idx] : 0; cnt[i] = d; s += d; }
  part[t] = s;
  __syncthreads();
  for (int off = 1; off < 1024; off <<= 1) {
    int v = (t >= off) ? part[t - off] : 0;
    __syncthreads();
    part[t] += v;
    __syncthreads();
  }
  int run = part[t] - s;                 // exclusive prefix
  for (int i = 0; i < CH; ++i) {
    int idx = base + i;
    if (idx < NN) {
      rowptr[idx] = run;
      invdeg[idx] = 1.0f / fmaxf((float)cnt[i], 1.0f);
      run += cnt[i];
    }
  }
  if (t == 0) rowptr[NN] = EE;
}

__global__ void k_fill(const int* __restrict__ src, const int* __restrict__ dst,
                       const int* __restrict__ rowptr, int* __restrict__ fill,
                       int* __restrict__ col) {
  int e = blockIdx.x * 256 + threadIdx.x;
  if (e < EE) {
    int d = dst[e];
    int p = atomicAdd(&fill[d], 1);
    col[rowptr[d] + p] = src[e];
  }
}

// ------------- per-(b,t) scalar aggregation: alpha = invdeg * sum x[src] -------------
__global__ __launch_bounds__(256) void k_axp(const float* __restrict__ xseq,
                                             const int* __restrict__ rowptr,
                                             const int* __restrict__ colg,
                                             const float* __restrict__ invdeg,
                                             float2* __restrict__ axp) {
  int q = blockIdx.x;                    // q = b*TT + t
  __shared__ float xl[NN];
  const float* xs = xseq + (size_t)q * NN;
  for (int i = threadIdx.x; i < NN; i += 256) xl[i] = xs[i];
  __syncthreads();
  for (int n = threadIdx.x; n < NN; n += 256) {
    int r0 = rowptr[n], r1 = rowptr[n + 1];
    float s = 0.f;
    for (int i = r0; i < r1; ++i) s += xl[colg[i]];
    axp[(size_t)q * NN + n] = make_float2(s * invdeg[n], xl[n]);
  }
}

// ------------- fused layer2: edge agg (h1 recomputed from (alpha,x)) + two-phase GEMM + mean -------------
__global__ __launch_bounds__(256) void k_conv2(const float2* __restrict__ axp,
    const int* __restrict__ rowptr, const int* __restrict__ colg,
    const float* __restrict__ invdeg,
    const float* __restrict__ wl1, const float* __restrict__ wr1, const float* __restrict__ b1,
    const float* __restrict__ Wl2, const float* __restrict__ Wr2, const float* __restrict__ b2,
    float* __restrict__ outs)
{
  __shared__ __align__(16) float At[64 * 68];    // [k][node], stride 68 (16B-aligned, conflict-free)
  __shared__ __align__(16) float2 eb[ECAP];
  __shared__ __align__(16) float part[16 * 64];
  const int q  = blockIdx.y;                     // b*TT + t
  const int n0 = blockIdx.x * NPB;
  const int tid = threadIdx.x;
  const float2* ax = axp + (size_t)q * NN;

  // stage this block's contiguous CSR edge range: (alpha,x) of each source node
  const int e0 = rowptr[n0];
  const int e1 = rowptr[min(n0 + NPB, NN)];
  const bool fits = (e1 - e0) <= ECAP;           // block-uniform; ~always true
  if (fits) {
    for (int i = e0 + tid; i < e1; i += 256) eb[i - e0] = ax[colg[i]];
  }
  __syncthreads();

  const int w = tid >> 6, lane = tid & 63;
  const float wlc = wl1[lane], wrc = wr1[lane], b1c = b1[lane];

  // ---- phase A: edge aggregation -> At[k=lane][node] ----
  for (int ii = 0; ii < 16; ++ii) {
    const int nl = w * 16 + ii;
    const int n  = n0 + nl;
    float agg = 0.f;
    if (n < NN) {
      const int r0 = __builtin_amdgcn_readfirstlane(rowptr[n]);
      const int r1 = __builtin_amdgcn_readfirstlane(rowptr[n + 1]);
      if (fits) {
        int i = r0 - e0;
        const int i1 = r1 - e0;
        float agg1 = 0.f;
        if ((i & 1) && i < i1) {                 // align to 16B pair
          float2 ab = eb[i];
          agg += fmaxf(fmaf(ab.x, wlc, fmaf(ab.y, wrc, b1c)), 0.f);
          ++i;
        }
        for (; i + 1 < i1; i += 2) {             // 2 edges per ds_read_b128
          float4 p = *(const float4*)&eb[i];
          agg  += fmaxf(fmaf(p.x, wlc, fmaf(p.y, wrc, b1c)), 0.f);
          agg1 += fmaxf(fmaf(p.z, wlc, fmaf(p.w, wrc, b1c)), 0.f);
        }
        if (i < i1) {
          float2 ab = eb[i];
          agg += fmaxf(fmaf(ab.x, wlc, fmaf(ab.y, wrc, b1c)), 0.f);
        }
        agg += agg1;
      } else {                                   // rare overflow path
        for (int i = r0; i < r1; ++i) {
          float2 ab = ax[colg[i]];
          agg += fmaxf(fmaf(ab.x, wlc, fmaf(ab.y, wrc, b1c)), 0.f);
        }
      }
      agg *= invdeg[n];
    }
    At[lane * 68 + nl] = agg;
  }
  __syncthreads();

  // ---- GEMM phase A: acc += agg2 @ Wl2 ----
  const int rq = lane >> 4, cc = lane & 15;
  const int rb = w * 16 + rq * 4;
  float acc[4][4] = {{0.f}};
  {
    const float4* W4 = (const float4*)Wl2;
    #pragma unroll
    for (int k = 0; k < 64; ++k) {
      const float4 wv = W4[k * 16 + cc];
      const float4 av = *(const float4*)&At[k * 68 + rb];
      const float ar[4] = {av.x, av.y, av.z, av.w};
      #pragma unroll
      for (int i = 0; i < 4; ++i) {
        acc[i][0] = fmaf(ar[i], wv.x, acc[i][0]);
        acc[i][1] = fmaf(ar[i], wv.y, acc[i][1]);
        acc[i][2] = fmaf(ar[i], wv.z, acc[i][2]);
        acc[i][3] = fmaf(ar[i], wv.w, acc[i][3]);
      }
    }
  }
  __syncthreads();

  // ---- phase B: overwrite At with h1own ----
  for (int ii = 0; ii < 16; ++ii) {
    const int nl = w * 16 + ii;
    const int n  = n0 + nl;
    float h = 0.f;
    if (n < NN) {
      float2 own = ax[n];
      h = fmaxf(fmaf(own.x, wlc, fmaf(own.y, wrc, b1c)), 0.f);
    }
    At[lane * 68 + nl] = h;
  }
  __syncthreads();

  // ---- GEMM phase B: acc += h1own @ Wr2 ----
  {
    const float4* W4 = (const float4*)Wr2;
    #pragma unroll
    for (int k = 0; k < 64; ++k) {
      const float4 wv = W4[k * 16 + cc];
      const float4 av = *(const float4*)&At[k * 68 + rb];
      const float ar[4] = {av.x, av.y, av.z, av.w};
      #pragma unroll
      for (int i = 0; i < 4; ++i) {
        acc[i][0] = fmaf(ar[i], wv.x, acc[i][0]);
        acc[i][1] = fmaf(ar[i], wv.y, acc[i][1]);
        acc[i][2] = fmaf(ar[i], wv.z, acc[i][2]);
        acc[i][3] = fmaf(ar[i], wv.w, acc[i][3]);
      }
    }
  }

  // bias + relu + column partial sums (mask invalid node rows)
  const float4 bias = ((const float4*)b2)[cc];
  float cs0 = 0.f, cs1 = 0.f, cs2 = 0.f, cs3 = 0.f;
  #pragma unroll
  for (int i = 0; i < 4; ++i) {
    if (n0 + rb + i < NN) {
      cs0 += fmaxf(acc[i][0] + bias.x, 0.f);
      cs1 += fmaxf(acc[i][1] + bias.y, 0.f);
      cs2 += fmaxf(acc[i][2] + bias.z, 0.f);
      cs3 += fmaxf(acc[i][3] + bias.w, 0.f);
    }
  }
  ((float4*)part)[(w * 4 + rq) * 16 + cc] = make_float4(cs0, cs1, cs2, cs3);
  __syncthreads();
  if (tid < 64) {
    float s = 0.f;
    #pragma unroll
    for (int g = 0; g < 16; ++g) s += part[g * 64 + tid];
    int b = q / TT, t = q % TT;
    atomicAdd(&outs[((size_t)t * BB + b) * 64 + tid], s);
  }
}

// ------------- GRU side -------------
__global__ void k_T(const float* __restrict__ Wih, const float* __restrict__ Whh,
                    float* __restrict__ WihT, float* __restrict__ WhhT) {
  int id = blockIdx.x * 256 + threadIdx.x;
  if (id < 384 * 64)  { int r = id / 64;  int c = id % 64;  WihT[c * 384 + r] = Wih[id]; }
  if (id < 384 * 128) { int r = id / 128; int c = id % 128; WhhT[c * 384 + r] = Whh[id]; }
}

__global__ __launch_bounds__(384) void k_gi(const float* __restrict__ outs,
                                            const float* __restrict__ WihT,
                                            const float* __restrict__ bih,
                                            float* __restrict__ gi) {
  int g = blockIdx.x;                   // t*BB + b
  __shared__ float xl[64];
  int r = threadIdx.x;
  if (r < 64) xl[r] = outs[(size_t)g * 64 + r] * (1.0f / (float)NN);
  __syncthreads();
  float acc = bih[r];
  #pragma unroll 8
  for (int c = 0; c < 64; ++c) acc = fmaf(WihT[c * 384 + r], xl[c], acc);
  gi[(size_t)g * 384 + r] = acc;
}

__global__ __launch_bounds__(384) void k_gru(const float* __restrict__ gi,
                                             const float* __restrict__ WhhT,
                                             const float* __restrict__ bhh,
                                             const float* __restrict__ h1W,
                                             const float* __restrict__ h1b,
                                             const float* __restrict__ h2W,
                                             const float* __restrict__ h2b,
                                             float* __restrict__ out) {
  int b = blockIdx.x, r = threadIdx.x;
  __shared__ float hl[128];
  __shared__ float ghl[384];
  __shared__ float t1l[64];
  float wreg[128];
  #pragma unroll
  for (int c = 0; c < 128; ++c) wreg[c] = WhhT[c * 384 + r];   // coalesced
  float bh = bhh[r];
  if (r < 128) hl[r] = 0.f;
  __syncthreads();
  for (int t = 0; t < TT; ++t) {
    float acc = bh;
    #pragma unroll
    for (int c = 0; c < 128; ++c) acc = fmaf(wreg[c], hl[c], acc);
    ghl[r] = acc;
    __syncthreads();
    if (r < 128) {
      const float* gio = gi + ((size_t)t * BB + b) * 384;
      float ir = gio[r], iz = gio[128 + r], inn = gio[256 + r];
      float hr = ghl[r], hz = ghl[128 + r], hn = ghl[256 + r];
      float rg = 1.f / (1.f + expf(-(ir + hr)));
      float zg = 1.f / (1.f + expf(-(iz + hz)));
      float ng = tanhf(inn + rg * hn);
      hl[r] = (1.f - zg) * ng + zg * hl[r];
    }
    __syncthreads();
  }
  if (r < 64) {
    float a = h1b[r];
    #pragma unroll
    for (int c = 0; c < 128; ++c) a = fmaf(hl[c], h1W[c * 64 + r], a);
    t1l[r] = fmaxf(a, 0.f);
  }
  __syncthreads();
  if (r == 0) {
    float o = h2b[0];
    for (int j = 0; j < 64; ++j) o = fmaf(t1l[j], h2W[j], o);
    out[b] = o;
  }
}

extern "C" void kernel_launch(void* const* d_in, const int* in_sizes, int n_in,
                              void* d_out, int out_size, void* d_ws, size_t ws_size,
                              hipStream_t stream) {
  const float* xseq = (const float*)d_in[0];
  const int*   ei   = (const int*)d_in[1];
  const float* s1Wl = (const float*)d_in[2];
  const float* s1Wr = (const float*)d_in[3];
  const float* s1b  = (const float*)d_in[4];
  const float* s2Wl = (const float*)d_in[5];
  const float* s2Wr = (const float*)d_in[6];
  const float* s2b  = (const float*)d_in[7];
  const float* gWih = (const float*)d_in[8];
  const float* gWhh = (const float*)d_in[9];
  const float* gbih = (const float*)d_in[10];
  const float* gbhh = (const float*)d_in[11];
  const float* h1W  = (const float*)d_in[12];
  const float* h1b  = (const float*)d_in[13];
  const float* h2W  = (const float*)d_in[14];
  const float* h2b  = (const float*)d_in[15];
  float* out = (float*)d_out;

  char* ws = (char*)d_ws;
  int*    deg    = (int*)(ws + 0);              //   20480
  int*    fill   = (int*)(ws + 20480);          //   20480
  float*  outs   = (float*)(ws + 40960);        //  262144 (T*B*64 sums)
  int*    rowptr = (int*)(ws + 303104);         //   20480
  float*  invdeg = (float*)(ws + 323584);       //   20480
  int*    col    = (int*)(ws + 344064);         //  320512
  float2* axp    = (float2*)(ws + 664576);      // 40960000 (B*T*N float2)
  float*  WihT   = (float*)(ws + 41624576);     //   98304
  float*  WhhT   = (float*)(ws + 41722880);     //  196608
  float*  gi     = (float*)(ws + 41919488);     // 1572864  (end ~43.5 MB)

  const int* srcI = ei;
  const int* dstI = ei + EE;

  hipMemsetAsync(d_ws, 0, 303104, stream);      // deg + fill + outs
  k_deg <<<(EE + 255) / 256, 256, 0, stream>>>(dstI, deg);
  k_scan<<<1, 1024, 0, stream>>>(deg, rowptr, invdeg);
  k_fill<<<(EE + 255) / 256, 256, 0, stream>>>(srcI, dstI, rowptr, fill, col);
  k_axp <<<BB * TT, 256, 0, stream>>>(xseq, rowptr, col, invdeg, axp);
  dim3 g2((NN + NPB - 1) / NPB, BB * TT);
  k_conv2<<<g2, 256, 0, stream>>>(axp, rowptr, col, invdeg,
                                  s1Wl, s1Wr, s1b, s2Wl, s2Wr, s2b, outs);
  k_T   <<<192, 256, 0, stream>>>(gWih, gWhh, WihT, WhhT);
  k_gi  <<<BB * TT, 384, 0, stream>>>(outs, WihT, gbih, gi);
  k_gru <<<BB, 384, 0, stream>>>(gi, WhhT, gbhh, h1W, h1b, h2W, h2b, out);
}

// Round 3
// 1862.974 us; speedup vs baseline: 37.6148x; 37.6148x over previous
//
#include <hip/hip_runtime.h>

#define NN 5000
#define EE 80000
#define BB 16
#define TT 64
// HG=64, HT=128

constexpr int NPB  = 64;    // nodes per conv2 block
constexpr int ECAP = 1280;  // LDS edge-stage capacity (mean 1024, +8 sigma)

// ---------------- CSR build ----------------
__global__ void k_deg(const int* __restrict__ dst, int* __restrict__ deg) {
  int e = blockIdx.x * 256 + threadIdx.x;
  if (e < EE) atomicAdd(&deg[dst[e]], 1);
}

__global__ __launch_bounds__(1024) void k_scan(const int* __restrict__ deg,
                                               int* __restrict__ rowptr,
                                               float* __restrict__ invdeg) {
  __shared__ int part[1024];
  int t = threadIdx.x;
  const int CH = 5;                      // 1024*5 >= 5000
  int base = t * CH;
  int cnt[CH];
  int s = 0;
  for (int i = 0; i < CH; ++i) { int idx = base + i; int d = (idx < NN) ? deg[idx] : 0; cnt[i] = d; s += d; }
  part[t] = s;
  __syncthreads();
  for (int off = 1; off < 1024; off <<= 1) {
    int v = (t >= off) ? part[t - off] : 0;
    __syncthreads();
    part[t] += v;
    __syncthreads();
  }
  int run = part[t] - s;                 // exclusive prefix
  for (int i = 0; i < CH; ++i) {
    int idx = base + i;
    if (idx < NN) {
      rowptr[idx] = run;
      invdeg[idx] = 1.0f / fmaxf((float)cnt[i], 1.0f);
      run += cnt[i];
    }
  }
  if (t == 0) rowptr[NN] = EE;
}

__global__ void k_fill(const int* __restrict__ src, const int* __restrict__ dst,
                       const int* __restrict__ rowptr, int* __restrict__ fill,
                       int* __restrict__ col) {
  int e = blockIdx.x * 256 + threadIdx.x;
  if (e < EE) {
    int d = dst[e];
    int p = atomicAdd(&fill[d], 1);
    col[rowptr[d] + p] = src[e];
  }
}

// ------------- per-(b,t) scalar aggregation: alpha = invdeg * sum x[src] -------------
__global__ __launch_bounds__(256) void k_axp(const float* __restrict__ xseq,
                                             const int* __restrict__ rowptr,
                                             const int* __restrict__ colg,
                                             const float* __restrict__ invdeg,
                                             float2* __restrict__ axp) {
  int q = blockIdx.x;                    // q = b*TT + t
  __shared__ float xl[NN];
  const float* xs = xseq + (size_t)q * NN;
  for (int i = threadIdx.x; i < NN; i += 256) xl[i] = xs[i];
  __syncthreads();
  for (int n = threadIdx.x; n < NN; n += 256) {
    int r0 = rowptr[n], r1 = rowptr[n + 1];
    float s = 0.f;
    for (int i = r0; i < r1; ++i) s += xl[colg[i]];
    axp[(size_t)q * NN + n] = make_float2(s * invdeg[n], xl[n]);
  }
}

// ------------- fused layer2: edge agg (h1 from (alpha,x)) + merged GEMM + mean -------------
__global__ __launch_bounds__(256) void k_conv2(const float2* __restrict__ axp,
    const int* __restrict__ rowptr, const int* __restrict__ colg,
    const float* __restrict__ invdeg,
    const float* __restrict__ wl1, const float* __restrict__ wr1, const float* __restrict__ b1,
    const float* __restrict__ Wl2, const float* __restrict__ Wr2, const float* __restrict__ b2,
    float* __restrict__ outs)
{
  __shared__ __align__(16) float At[64 * 65];    // [k][node], stride 65 (odd -> conflict-free)
  __shared__ __align__(16) float2 eb[ECAP];
  const int q  = blockIdx.y;                     // b*TT + t
  const int n0 = blockIdx.x * NPB;
  const int tid = threadIdx.x;
  const float2* ax = axp + (size_t)q * NN;

  // stage this block's contiguous CSR edge range: (alpha,x) of each source node
  const int e0 = __builtin_amdgcn_readfirstlane(rowptr[n0]);
  const int e1 = __builtin_amdgcn_readfirstlane(rowptr[min(n0 + NPB, NN)]);
  const bool fits = (e1 - e0) <= ECAP;           // block-uniform; ~always true
  if (fits) {
    for (int i = e0 + tid; i < e1; i += 256) eb[i - e0] = ax[colg[i]];
  }
  __syncthreads();

  const int w = tid >> 6, lane = tid & 63;

  // ---- phase A: edge aggregation -> At[k=lane][node] ----
  {
    const float wlc = wl1[lane], wrc = wr1[lane], b1c = b1[lane];
    int rprev = __builtin_amdgcn_readfirstlane(rowptr[min(n0 + w * 16, NN)]);
    for (int ii = 0; ii < 16; ++ii) {
      const int nl = w * 16 + ii;
      const int n  = n0 + nl;
      const int rnext = __builtin_amdgcn_readfirstlane(rowptr[min(n + 1, NN)]);
      float agg = 0.f;
      if (n < NN) {
        const int r0 = rprev, r1 = rnext;
        if (fits) {
          int i = r0 - e0;
          const int i1 = r1 - e0;
          float agg1 = 0.f;
          if ((i & 1) && i < i1) {               // align to 16B pair
            float2 ab = eb[i];
            agg += fmaxf(fmaf(ab.x, wlc, fmaf(ab.y, wrc, b1c)), 0.f);
            ++i;
          }
          for (; i + 1 < i1; i += 2) {           // 2 edges per ds_read_b128 (broadcast)
            float4 p = *(const float4*)&eb[i];
            agg  += fmaxf(fmaf(p.x, wlc, fmaf(p.y, wrc, b1c)), 0.f);
            agg1 += fmaxf(fmaf(p.z, wlc, fmaf(p.w, wrc, b1c)), 0.f);
          }
          if (i < i1) {
            float2 ab = eb[i];
            agg += fmaxf(fmaf(ab.x, wlc, fmaf(ab.y, wrc, b1c)), 0.f);
          }
          agg += agg1;
        } else {                                 // rare overflow path
          for (int i = r0; i < r1; ++i) {
            float2 ab = ax[colg[i]];
            agg += fmaxf(fmaf(ab.x, wlc, fmaf(ab.y, wrc, b1c)), 0.f);
          }
        }
        agg *= invdeg[n];
      }
      At[lane * 65 + nl] = agg;                  // bank: (lane+nl)%32 -> conflict-free
      rprev = rnext;
    }
  }
  __syncthreads();

  // ---- merged GEMM: acc[j] = sum_k agg[k][r]*Wl2[k][c0+j] + h1own(k)*Wr2[k][c0+j] ----
  const int r  = tid & 63;
  const int cg = __builtin_amdgcn_readfirstlane(tid >> 6);  // wave-uniform -> scalar W loads
  const int c0 = cg * 16;
  const bool valid = (n0 + r) < NN;
  const float2 own = valid ? ax[n0 + r] : make_float2(0.f, 0.f);
  float acc[16];
  #pragma unroll
  for (int j = 0; j < 16; ++j) acc[j] = 0.f;

  #pragma unroll 2
  for (int k = 0; k < 64; ++k) {
    const float a = At[k * 65 + r];              // 1 ds_read_b32, conflict-free
    const float h = fmaxf(fmaf(own.x, wl1[k], fmaf(own.y, wr1[k], b1[k])), 0.f);
    const float* __restrict__ wl = Wl2 + k * 64 + c0;   // uniform -> s_load
    const float* __restrict__ wr = Wr2 + k * 64 + c0;
    #pragma unroll
    for (int j = 0; j < 16; ++j)
      acc[j] = fmaf(a, wl[j], fmaf(h, wr[j], acc[j]));
  }
  __syncthreads();                               // At free now

  // ---- epilogue: bias + relu, stash per-node rows, column-sum, one atomic ----
  #pragma unroll
  for (int j = 0; j < 16; ++j) {
    float v = fmaxf(acc[j] + b2[c0 + j], 0.f);
    At[r * 65 + c0 + j] = valid ? v : 0.f;       // bank (r + c0+j)%32 -> conflict-free
  }
  __syncthreads();
  if (tid < 64) {
    float s = 0.f;
    for (int rr = 0; rr < 64; ++rr) s += At[rr * 65 + tid];
    int b = q / TT, t = q % TT;
    atomicAdd(&outs[((size_t)t * BB + b) * 64 + tid], s);
  }
}

// ------------- GRU side -------------
__global__ void k_T(const float* __restrict__ Wih, const float* __restrict__ Whh,
                    float* __restrict__ WihT, float* __restrict__ WhhT) {
  int id = blockIdx.x * 256 + threadIdx.x;
  if (id < 384 * 64)  { int r = id / 64;  int c = id % 64;  WihT[c * 384 + r] = Wih[id]; }
  if (id < 384 * 128) { int r = id / 128; int c = id % 128; WhhT[c * 384 + r] = Whh[id]; }
}

__global__ __launch_bounds__(384) void k_gi(const float* __restrict__ outs,
                                            const float* __restrict__ WihT,
                                            const float* __restrict__ bih,
                                            float* __restrict__ gi) {
  int g = blockIdx.x;                   // t*BB + b
  __shared__ float xl[64];
  int r = threadIdx.x;
  if (r < 64) xl[r] = outs[(size_t)g * 64 + r] * (1.0f / (float)NN);
  __syncthreads();
  float acc = bih[r];
  #pragma unroll 8
  for (int c = 0; c < 64; ++c) acc = fmaf(WihT[c * 384 + r], xl[c], acc);
  gi[(size_t)g * 384 + r] = acc;
}

__global__ __launch_bounds__(384) void k_gru(const float* __restrict__ gi,
                                             const float* __restrict__ WhhT,
                                             const float* __restrict__ bhh,
                                             const float* __restrict__ h1W,
                                             const float* __restrict__ h1b,
                                             const float* __restrict__ h2W,
                                             const float* __restrict__ h2b,
                                             float* __restrict__ out) {
  int b = blockIdx.x, r = threadIdx.x;
  __shared__ float hl[128];
  __shared__ float ghl[384];
  __shared__ float t1l[64];
  float wreg[128];
  #pragma unroll
  for (int c = 0; c < 128; ++c) wreg[c] = WhhT[c * 384 + r];   // coalesced
  float bh = bhh[r];
  if (r < 128) hl[r] = 0.f;
  __syncthreads();
  for (int t = 0; t < TT; ++t) {
    float acc = bh;
    #pragma unroll
    for (int c = 0; c < 128; ++c) acc = fmaf(wreg[c], hl[c], acc);
    ghl[r] = acc;
    __syncthreads();
    if (r < 128) {
      const float* gio = gi + ((size_t)t * BB + b) * 384;
      float ir = gio[r], iz = gio[128 + r], inn = gio[256 + r];
      float hr = ghl[r], hz = ghl[128 + r], hn = ghl[256 + r];
      float rg = 1.f / (1.f + expf(-(ir + hr)));
      float zg = 1.f / (1.f + expf(-(iz + hz)));
      float ng = tanhf(inn + rg * hn);
      hl[r] = (1.f - zg) * ng + zg * hl[r];
    }
    __syncthreads();
  }
  if (r < 64) {
    float a = h1b[r];
    #pragma unroll
    for (int c = 0; c < 128; ++c) a = fmaf(hl[c], h1W[c * 64 + r], a);
    t1l[r] = fmaxf(a, 0.f);
  }
  __syncthreads();
  if (r == 0) {
    float o = h2b[0];
    for (int j = 0; j < 64; ++j) o = fmaf(t1l[j], h2W[j], o);
    out[b] = o;
  }
}

extern "C" void kernel_launch(void* const* d_in, const int* in_sizes, int n_in,
                              void* d_out, int out_size, void* d_ws, size_t ws_size,
                              hipStream_t stream) {
  const float* xseq = (const float*)d_in[0];
  const int*   ei   = (const int*)d_in[1];
  const float* s1Wl = (const float*)d_in[2];
  const float* s1Wr = (const float*)d_in[3];
  const float* s1b  = (const float*)d_in[4];
  const float* s2Wl = (const float*)d_in[5];
  const float* s2Wr = (const float*)d_in[6];
  const float* s2b  = (const float*)d_in[7];
  const float* gWih = (const float*)d_in[8];
  const float* gWhh = (const float*)d_in[9];
  const float* gbih = (const float*)d_in[10];
  const float* gbhh = (const float*)d_in[11];
  const float* h1W  = (const float*)d_in[12];
  const float* h1b  = (const float*)d_in[13];
  const float* h2W  = (const float*)d_in[14];
  const float* h2b  = (const float*)d_in[15];
  float* out = (float*)d_out;

  char* ws = (char*)d_ws;
  int*    deg    = (int*)(ws + 0);              //   20480
  int*    fill   = (int*)(ws + 20480);          //   20480
  float*  outs   = (float*)(ws + 40960);        //  262144 (T*B*64 sums)
  int*    rowptr = (int*)(ws + 303104);         //   20480
  float*  invdeg = (float*)(ws + 323584);       //   20480
  int*    col    = (int*)(ws + 344064);         //  320512
  float2* axp    = (float2*)(ws + 664576);      // 40960000 (B*T*N float2)
  float*  WihT   = (float*)(ws + 41624576);     //   98304
  float*  WhhT   = (float*)(ws + 41722880);     //  196608
  float*  gi     = (float*)(ws + 41919488);     // 1572864  (end ~43.5 MB)

  const int* srcI = ei;
  const int* dstI = ei + EE;

  hipMemsetAsync(d_ws, 0, 303104, stream);      // deg + fill + outs
  k_deg <<<(EE + 255) / 256, 256, 0, stream>>>(dstI, deg);
  k_scan<<<1, 1024, 0, stream>>>(deg, rowptr, invdeg);
  k_fill<<<(EE + 255) / 256, 256, 0, stream>>>(srcI, dstI, rowptr, fill, col);
  k_axp <<<BB * TT, 256, 0, stream>>>(xseq, rowptr, col, invdeg, axp);
  dim3 g2((NN + NPB - 1) / NPB, BB * TT);
  k_conv2<<<g2, 256, 0, stream>>>(axp, rowptr, col, invdeg,
                                  s1Wl, s1Wr, s1b, s2Wl, s2Wr, s2b, outs);
  k_T   <<<192, 256, 0, stream>>>(gWih, gWhh, WihT, WhhT);
  k_gi  <<<BB * TT, 384, 0, stream>>>(outs, WihT, gbih, gi);
  k_gru <<<BB, 384, 0, stream>>>(gi, WhhT, gbhh, h1W, h1b, h2W, h2b, out);
}